// Round 1
// baseline (807.623 us; speedup 1.0000x reference)
//
#include <hip/hip_runtime.h>

// CorrAttentionBias: out = attn + (neigh_bias + sink_bias) broadcast over H,
// then NEG where mask[b,j] (col) or mask[b,i] (row).
// Shapes: attn (B=2, H=16, L=2048, L), c_local/c_sink/mask (B, L).
//
// Derived semantics from the reference's .at[].set overwrite order:
//   j == i+1 : neigh = ALPHA * c_local[b, i+1]
//   j == i-1 : neigh = ALPHA * c_local[b, (i==1 || i==L-1) ? i : i-1]
// Masked entries are exactly NEG.

#define ALPHA 0.5f
#define BETA  0.1f
#define NEG   -100000.0f

constexpr int Bc = 2;
constexpr int Hc = 16;
constexpr int Lc = 2048;

__global__ __launch_bounds__(256) void corr_bias_kernel(
    const float* __restrict__ attn,
    const float* __restrict__ c_local,
    const float* __restrict__ c_sink,
    const int*   __restrict__ mask,
    float*       __restrict__ out)
{
    const int row = blockIdx.x;              // row = ((b*H)+h)*L + i
    const int i   = row & (Lc - 1);
    const int b   = row >> 15;               // row / (H*L), H*L = 32768
    const int tid = threadIdx.x;

    const size_t rowoff = (size_t)row * Lc;
    const float* arow = attn + rowoff;
    float*       orow = out  + rowoff;

    // Row masked: whole row is NEG — skip the attn read entirely (saves ~50% of fetch).
    if (mask[b * Lc + i]) {
        const float4 neg4 = make_float4(NEG, NEG, NEG, NEG);
        reinterpret_cast<float4*>(orow)[tid]       = neg4;
        reinterpret_cast<float4*>(orow)[tid + 256] = neg4;
        return;
    }

    const float cs_i = c_sink[b * Lc + i];
    float a_p = 0.0f, a_m = 0.0f;
    if (i < Lc - 1) a_p = ALPHA * c_local[b * Lc + i + 1];
    if (i >= 1) {
        const int src = (i == 1 || i == Lc - 1) ? i : (i - 1);
        a_m = ALPHA * c_local[b * Lc + src];
    }

    const float4* csrow = reinterpret_cast<const float4*>(c_sink + b * Lc);
    const int4*   mrow  = reinterpret_cast<const int4*>(mask + b * Lc);

    #pragma unroll
    for (int r = 0; r < 2; ++r) {
        const int v  = tid + r * 256;        // float4 index within the row (0..511)
        const int j0 = v * 4;

        const float4 a4  = reinterpret_cast<const float4*>(arow)[v];
        const float4 cs4 = csrow[v];
        const int4   m4  = mrow[v];

        const float av[4] = {a4.x, a4.y, a4.z, a4.w};
        const float cv[4] = {cs4.x, cs4.y, cs4.z, cs4.w};
        const int   mv[4] = {m4.x, m4.y, m4.z, m4.w};
        float o[4];

        #pragma unroll
        for (int k = 0; k < 4; ++k) {
            const int j = j0 + k;
            float bias = BETA * cs_i * cv[k];
            if (j == i - 1) bias += a_m;
            if (j == i + 1) bias += a_p;
            o[k] = mv[k] ? NEG : (av[k] + bias);
        }

        reinterpret_cast<float4*>(orow)[v] = make_float4(o[0], o[1], o[2], o[3]);
    }
}

extern "C" void kernel_launch(void* const* d_in, const int* in_sizes, int n_in,
                              void* d_out, int out_size, void* d_ws, size_t ws_size,
                              hipStream_t stream) {
    const float* attn    = (const float*)d_in[0];
    const float* c_local = (const float*)d_in[1];
    const float* c_sink  = (const float*)d_in[2];
    const int*   mask    = (const int*)d_in[3];
    float*       out     = (float*)d_out;

    const int nrows = Bc * Hc * Lc;          // 65536 blocks, one per (b,h,i) row
    corr_bias_kernel<<<dim3(nrows), dim3(256), 0, stream>>>(attn, c_local, c_sink, mask, out);
}